// Round 11
// baseline (301.774 us; speedup 1.0000x reference)
//
#include <hip/hip_runtime.h>
#include <hip/hip_bf16.h>
#include <math.h>

#define B_   8192
#define F_   48
#define T_   512
#define L_   8
#define THR  256
#define NW   4           // waves per block
#define HST  520         // H LDS row stride in shorts (1040B; 65 uint4; 2-way banks)
#define DST  72          // staging row stride in shorts (144B -> 2-way banks, free)

typedef unsigned short ushort_t;
typedef unsigned int   uint_t;
typedef __attribute__((ext_vector_type(8))) short short8;
typedef __attribute__((ext_vector_type(4))) float f32x4;

#define MFMA(a,b,c) __builtin_amdgcn_mfma_f32_16x16x32_bf16(a,b,c,0,0,0)

__device__ inline ushort_t f2bf(float x) {
    __hip_bfloat16 h = __float2bfloat16(x);
    return *reinterpret_cast<ushort_t*>(&h);
}
__device__ inline float bf2f(ushort_t x) {
    __hip_bfloat16 h;
    *reinterpret_cast<ushort_t*>(&h) = x;
    return __bfloat162float(h);
}
__device__ inline short8 negbf(short8 v) {
    short8 r;
    #pragma unroll
    for (int i = 0; i < 8; ++i) r[i] = v[i] ^ (short)0x8000;
    return r;
}

// block-wide multi-value reduce: wave butterfly, leaders -> redL[q*NW + wave]
template<int NQ>
__device__ inline void reduce_vals(float* v, float* redL, int wave, int lane) {
    #pragma unroll
    for (int s = 32; s > 0; s >>= 1)
        #pragma unroll
        for (int q = 0; q < NQ; ++q) v[q] += __shfl_xor(v[q], s, 64);
    __syncthreads();                  // protect prior redL use / order LDS writes
    if (lane == 0)
        #pragma unroll
        for (int q = 0; q < NQ; ++q) redL[q * NW + wave] = v[q];
    __syncthreads();
}

// sharded barrier: SH counters on separate 128B lines
template<int SH>
__device__ inline void bar_add(uint_t* cnt, int blk) {
    __hip_atomic_fetch_add(&cnt[(blk & (SH - 1)) * 32], 1u, __ATOMIC_RELEASE,
                           __HIP_MEMORY_SCOPE_AGENT);
}
template<int SH>
__device__ inline void bar_wait(uint_t* cnt, uint_t tgt) {
    if (threadIdx.x == 0) {
        for (;;) {
            uint_t s = 0;
            #pragma unroll
            for (int i = 0; i < SH; ++i)
                s += __hip_atomic_load(&cnt[i * 32], __ATOMIC_RELAXED, __HIP_MEMORY_SCOPE_AGENT);
            if (s >= tgt) break;
            __builtin_amdgcn_s_sleep(2);
        }
        (void)__hip_atomic_load(&cnt[0], __ATOMIC_ACQUIRE, __HIP_MEMORY_SCOPE_AGENT);
    }
    __syncthreads();
}
__device__ inline float aload(const float* p) {
    return __hip_atomic_load(p, __ATOMIC_RELAXED, __HIP_MEMORY_SCOPE_AGENT);
}
__device__ inline void astore(float* p, float v) {
    __hip_atomic_store(p, v, __ATOMIC_RELAXED, __HIP_MEMORY_SCOPE_AGENT);
}

// soft-threshold on a packed bf16 pair (layer-0 act pass)
__device__ inline uint_t act2(uint_t v, float lam, float th1, float& cnt_) {
    float lo = __uint_as_float(v << 16);
    float hi = __uint_as_float(v & 0xffff0000u);
    float ml = fabsf(lo), mh = fabsf(hi);
    float fl = th1 * copysignf(fmaxf(ml - lam, 0.f), lo);
    float fh = th1 * copysignf(fmaxf(mh - lam, 0.f), hi);
    cnt_ += ((ml > lam) ? 1.f : 0.f) + ((mh > lam) ? 1.f : 0.f);
    return ((uint_t)f2bf(fl)) | (((uint_t)f2bf(fh)) << 16);
}

// ---------- prep: frag-linear bf16 layouts + zero barrier shards ----------
// Af: [L][tile32][k2(2)][quad4][m16][8]  (fwd B-frags)
// At: [L][ft3][ks16][quad4][m16][8]      (bwd B-frags)
// Df: [ft3][ks16][quad4][m16][8]         (final B-frags)
__global__ __launch_bounds__(256) void k_pre(
    const float* __restrict__ Ar, const float* __restrict__ Ai,
    const float* __restrict__ Dr, const float* __restrict__ Di,
    ushort_t* __restrict__ Afr, ushort_t* __restrict__ Afi,
    ushort_t* __restrict__ Atr, ushort_t* __restrict__ Ati,
    ushort_t* __restrict__ Dfr, ushort_t* __restrict__ Dfi,
    uint_t* __restrict__ cnt)
{
    const int gt = blockIdx.x * 256 + threadIdx.x;
    const int gs = gridDim.x * 256;
    if (gt < 1024) cnt[gt] = 0u;
    for (int idx = gt; idx < L_ * 32768; idx += gs) {
        int j = idx & 7, rest = idx >> 3;
        int mm = rest & 15; rest >>= 4;
        int qq = rest & 3;  rest >>= 2;
        int k2 = rest & 1;  rest >>= 1;
        int tile = rest & 31;
        int l = rest >> 5;
        int t = tile * 16 + mm, k = k2 * 32 + qq * 8 + j;
        float vr = 0.f, vi = 0.f;
        if (k < 48) { int g = l * 24576 + t * 48 + k; vr = Ar[g]; vi = Ai[g]; }
        Afr[idx] = f2bf(vr); Afi[idx] = f2bf(vi);
    }
    for (int idx = gt; idx < L_ * 24576; idx += gs) {
        int j = idx & 7, rest = idx >> 3;
        int mm = rest & 15; rest >>= 4;
        int qq = rest & 3;  rest >>= 2;
        int ks = rest & 15; rest >>= 4;
        int ft = rest % 3;
        int l = rest / 3;
        int f = ft * 16 + mm, k = ks * 32 + qq * 8 + j;
        int g = l * 24576 + k * 48 + f;
        Atr[idx] = f2bf(Ar[g]); Ati[idx] = f2bf(Ai[g]);
    }
    for (int idx = gt; idx < 24576; idx += gs) {
        int j = idx & 7, rest = idx >> 3;
        int mm = rest & 15; rest >>= 4;
        int qq = rest & 3;  rest >>= 2;
        int ks = rest & 15;
        int ft = rest >> 4;
        int f = ft * 16 + mm, k = ks * 32 + qq * 8 + j;
        Dfr[idx] = f2bf(Dr[k * 48 + f]); Dfi[idx] = f2bf(Di[k * 48 + f]);
    }
}

// forward GEMM from staging buffers: R = (ADDH ? H : 0) + s@A^T -> H (bf16 LDS)
template<int RPB, bool ADDH>
__device__ inline void gemmA(const ushort_t* Aflr, const ushort_t* Afli,
    const ushort_t* dbr, const ushort_t* dbi, ushort_t* HreL, ushort_t* HimL,
    int wave, int lane, int quad, int m)
{
    short8 dr0 = *(const short8*)&dbr[m * DST + quad * 8];
    short8 dr1 = *(const short8*)&dbr[m * DST + 32 + quad * 8];
    short8 di0 = *(const short8*)&dbi[m * DST + quad * 8];
    short8 di1 = *(const short8*)&dbi[m * DST + 32 + quad * 8];
    short8 din0 = negbf(di0), din1 = negbf(di1);
    #pragma unroll
    for (int ct = 0; ct < 8; ++ct) {
        const int tile = wave * 8 + ct;
        const ushort_t* rp = Aflr + (size_t)(tile * 2) * 512 + lane * 8;
        const ushort_t* ip = Afli + (size_t)(tile * 2) * 512 + lane * 8;
        short8 ar0 = *(const short8*)rp;
        short8 ar1 = *(const short8*)(rp + 512);
        short8 ai0 = *(const short8*)ip;
        short8 ai1 = *(const short8*)(ip + 512);
        f32x4 accR = {0.f,0.f,0.f,0.f}, accI = {0.f,0.f,0.f,0.f};
        accR = MFMA(dr0, ar0, accR);
        accR = MFMA(dr1, ar1, accR);
        accR = MFMA(din0, ai0, accR);
        accR = MFMA(din1, ai1, accR);
        accI = MFMA(dr0, ai0, accI);
        accI = MFMA(dr1, ai1, accI);
        accI = MFMA(di0, ar0, accI);
        accI = MFMA(di1, ar1, accI);
        const int t = tile * 16 + m;
        #pragma unroll
        for (int reg = 0; reg < 4; ++reg) {
            const int lr = quad * 4 + reg;
            if (RPB == 16 || lr < RPB) {
                float Rr = accR[reg], Ri = accI[reg];
                if (ADDH) { Rr += bf2f(HreL[lr * HST + t]); Ri += bf2f(HimL[lr * HST + t]); }
                HreL[lr * HST + t] = f2bf(Rr);
                HimL[lr * HST + t] = f2bf(Ri);
            }
        }
    }
}

// GEMM-B: R = H + s@A^T, fused activation -> Hn, counts
template<int RPB>
__device__ inline void gemmB(const ushort_t* Aflr, const ushort_t* Afli,
    const ushort_t* dbr, const ushort_t* dbi, ushort_t* HreL, ushort_t* HimL,
    float lam, float th1, float& cr, float& ci,
    int wave, int lane, int quad, int m)
{
    short8 zr0 = *(const short8*)&dbr[m * DST + quad * 8];
    short8 zr1 = *(const short8*)&dbr[m * DST + 32 + quad * 8];
    short8 zi0 = *(const short8*)&dbi[m * DST + quad * 8];
    short8 zi1 = *(const short8*)&dbi[m * DST + 32 + quad * 8];
    short8 zin0 = negbf(zi0), zin1 = negbf(zi1);
    #pragma unroll
    for (int ct = 0; ct < 8; ++ct) {
        const int tile = wave * 8 + ct;
        const ushort_t* rp = Aflr + (size_t)(tile * 2) * 512 + lane * 8;
        const ushort_t* ip = Afli + (size_t)(tile * 2) * 512 + lane * 8;
        short8 ar0 = *(const short8*)rp;
        short8 ar1 = *(const short8*)(rp + 512);
        short8 ai0 = *(const short8*)ip;
        short8 ai1 = *(const short8*)(ip + 512);
        f32x4 accR = {0.f,0.f,0.f,0.f}, accI = {0.f,0.f,0.f,0.f};
        accR = MFMA(zr0, ar0, accR);
        accR = MFMA(zr1, ar1, accR);
        accR = MFMA(zin0, ai0, accR);
        accR = MFMA(zin1, ai1, accR);
        accI = MFMA(zr0, ai0, accI);
        accI = MFMA(zr1, ai1, accI);
        accI = MFMA(zi0, ar0, accI);
        accI = MFMA(zi1, ar1, accI);
        const int t = tile * 16 + m;
        #pragma unroll
        for (int reg = 0; reg < 4; ++reg) {
            const int lr = quad * 4 + reg;
            if (RPB == 16 || lr < RPB) {
                float Rr = bf2f(HreL[lr * HST + t]) + accR[reg];
                float Ri = bf2f(HimL[lr * HST + t]) + accI[reg];
                float mr = fabsf(Rr), mi = fabsf(Ri);
                float fr = th1 * copysignf(fmaxf(mr - lam, 0.f), Rr);
                float fi = th1 * copysignf(fmaxf(mi - lam, 0.f), Ri);
                cr += (mr > lam) ? 1.f : 0.f;
                ci += (mi > lam) ? 1.f : 0.f;
                HreL[lr * HST + t] = f2bf(fr);
                HimL[lr * HST + t] = f2bf(fi);
            }
        }
    }
}

// backward/final GEMM: h = Hn @ B; wave ft<3 does its 16-col third, full K=512
template<int RPB>
__device__ inline void bwd_gemm(const ushort_t* Br, const ushort_t* Bi,
    const ushort_t* HreL, const ushort_t* HimL, float* pR, float* pI,
    int wave, int lane, int quad, int m)
{
    if (wave < 3) {
        const int ft = wave;
        f32x4 aR = {0.f,0.f,0.f,0.f}, aI = {0.f,0.f,0.f,0.f};
        #pragma unroll
        for (int ks = 0; ks < 16; ++ks) {
            const int k0 = ks * 32 + quad * 8;
            short8 hr = {0,0,0,0,0,0,0,0}, hi = {0,0,0,0,0,0,0,0};
            if (RPB == 16 || m < RPB) {
                hr = *(const short8*)&HreL[m * HST + k0];
                hi = *(const short8*)&HimL[m * HST + k0];
            }
            short8 hin = negbf(hi);
            short8 br = *(const short8*)(Br + (size_t)((ft * 16 + ks) * 64 + lane) * 8);
            short8 bi = *(const short8*)(Bi + (size_t)((ft * 16 + ks) * 64 + lane) * 8);
            aR = MFMA(hr, br, aR);
            aR = MFMA(hin, bi, aR);
            aI = MFMA(hr, bi, aI);
            aI = MFMA(hi, br, aI);
        }
        #pragma unroll
        for (int reg = 0; reg < 4; ++reg) {
            pR[(ft * 16 + quad * 4 + reg) * 17 + m] = aR[reg];
            pI[(ft * 16 + quad * 4 + reg) * 17 + m] = aI[reg];
        }
    }
}

// ---------- persistent cooperative kernel (templated on rows/block) ----------
// RPB=8: 1024 blocks, ~27.9KB LDS -> 4 blocks/CU (16 waves/CU), chosen only if
// the occupancy query confirms 4; RPB=16: 512 blocks, ~44.5KB, safe fallback.
template<int RPB>
__global__ __launch_bounds__(THR, 2) void k_lamp(
    const float* __restrict__ u,
    const ushort_t* __restrict__ Afr, const ushort_t* __restrict__ Afi,
    const ushort_t* __restrict__ Atr, const ushort_t* __restrict__ Ati,
    const ushort_t* __restrict__ Dfr, const ushort_t* __restrict__ Dfi,
    const float* __restrict__ th,
    float* part, uint_t* cnt,
    float* __restrict__ out)
{
    constexpr int NBLK  = B_ / RPB;
    constexpr int SH    = (NBLK > 512) ? 32 : 16;
    constexpr int PLOAD = NBLK / THR;
    constexpr int NELEM = RPB * F_;
    constexpr int ZPT   = (NELEM + THR - 1) / THR;
    constexpr bool EXACT = (NELEM % THR) == 0;

    extern __shared__ char dyn[];
    float*    pR   = (float*)dyn;                  // 3*16*17*4 = 3264
    float*    pI   = pR + 3 * 16 * 17;             // 3264
    float*    redL = pI + 3 * 16 * 17;             // 128
    ushort_t* dbr  = (ushort_t*)(redL + 32);       // 16*72*2 = 2304
    ushort_t* dbi  = dbr + 16 * DST;               // 2304
    ushort_t* HreL = dbi + 16 * DST;               // RPB*1040
    ushort_t* HimL = HreL + RPB * HST;             // RPB*1040

    const int tid = threadIdx.x, blk = blockIdx.x;
    const int row0 = blk * RPB;
    const int wave = tid >> 6, lane = tid & 63;
    const int quad = lane >> 4, m = lane & 15;
    const float2* u2 = (const float2*)u;
    uint_t tgt = NBLK;

    // zero staging buffers fully (rows>=RPB and pad cols stay 0 forever)
    {
        uint_t* z32 = (uint_t*)dbr;        // 2*16*72*2/4 = 1152 uints
        for (int i = tid; i < 16 * DST; i += THR) z32[i] = 0u;
    }
    __syncthreads();

    float zR[ZPT], zI[ZPT], dRr[ZPT], dIr[ZPT];
    // prologue: u -> z regs + bf16 staging; sigma0 partial; arrive
    {
        float acc = 0.f;
        #pragma unroll
        for (int k = 0; k < ZPT; ++k) {
            int j = tid + k * THR;
            zR[k] = 0.f; zI[k] = 0.f;
            if (EXACT || j < NELEM) {
                int r = j / 48, f = j - r * 48;
                float2 v = u2[(row0 + r) * 48 + f];
                zR[k] = v.x; zI[k] = v.y;
                dbr[r * DST + f] = f2bf(v.x);
                dbi[r * DST + f] = f2bf(v.y);
                acc += v.x * v.x + v.y * v.y;
            }
        }
        float v[1] = {acc};
        reduce_vals<1>(v, redL, wave, lane);
        if (tid == 0) astore(&part[blk * 8], redL[0] + redL[1] + redL[2] + redL[3]);
        __syncthreads();
        if (tid == 0) bar_add<SH>(cnt, blk);
    }

    // layer-0 forward (hides init barrier): R = u@A0^T
    gemmA<RPB, false>(Afr, Afi, dbr, dbi, HreL, HimL, wave, lane, quad, m);

    bar_wait<SH>(cnt, tgt);
    float lam, th1;
    {
        float v[1] = {0.f};
        #pragma unroll
        for (int i = 0; i < PLOAD; ++i) v[0] += aload(&part[(tid + i * THR) * 8]);
        reduce_vals<1>(v, redL, wave, lane);
        float sig2 = redL[0] + redL[1] + redL[2] + redL[3];
        lam = th[0] * sqrtf(sig2 * (1.0f / 48.0f));
        th1 = th[1];
    }

    // layer-0 activation pass over H, counts
    float cr = 0.f, ci = 0.f;
    {
        uint4* Hr4 = (uint4*)HreL;
        uint4* Hi4 = (uint4*)HimL;
        constexpr int IT0 = RPB * 64 / THR;
        #pragma unroll
        for (int k = 0; k < IT0; ++k) {
            int j = tid + k * THR;
            int r = j >> 6, c4 = j & 63;
            uint4* pr = Hr4 + r * 65 + c4;
            uint4* pi = Hi4 + r * 65 + c4;
            uint4 xr = *pr, xi = *pi;
            xr.x = act2(xr.x, lam, th1, cr); xr.y = act2(xr.y, lam, th1, cr);
            xr.z = act2(xr.z, lam, th1, cr); xr.w = act2(xr.w, lam, th1, cr);
            xi.x = act2(xi.x, lam, th1, ci); xi.y = act2(xi.y, lam, th1, ci);
            xi.z = act2(xi.z, lam, th1, ci); xi.w = act2(xi.w, lam, th1, ci);
            *pr = xr; *pi = xi;
        }
        __syncthreads();
    }

    for (int l = 0; l < L_ - 1; ++l) {
        // backward GEMM (3 waves, full K), results -> pR/pI
        bwd_gemm<RPB>(Atr + (size_t)l * 24576, Ati + (size_t)l * 24576,
                      HreL, HimL, pR, pI, wave, lane, quad, m);
        __syncthreads();

        // S-pass: d = u - h in regs + bf16 staging; expansion sums
        float S1 = 0.f, S2r = 0.f, S2i = 0.f, S3r = 0.f, S3i = 0.f;
        #pragma unroll
        for (int k = 0; k < ZPT; ++k) {
            int j = tid + k * THR;
            dRr[k] = 0.f; dIr[k] = 0.f;
            if (EXACT || j < NELEM) {
                int r = j / 48, f = j - r * 48;
                int ft = f >> 4, c = f & 15;
                float hR = pR[(ft * 16 + r) * 17 + c];
                float hI = pI[(ft * 16 + r) * 17 + c];
                float2 uv = u2[(row0 + r) * 48 + f];
                float dr = uv.x - hR, di = uv.y - hI;
                dRr[k] = dr; dIr[k] = di;
                dbr[r * DST + f] = f2bf(dr);
                dbi[r * DST + f] = f2bf(di);
                S1  += dr * dr + di * di;
                S2r += dr * zR[k]; S2i += di * zI[k];
                S3r += zR[k] * zR[k]; S3i += zI[k] * zI[k];
            }
        }
        // publish {cr, ci, S1, S2r, S2i, S3r, S3i}; arrive (one barrier/layer)
        {
            float v[7] = {cr, ci, S1, S2r, S2i, S3r, S3i};
            reduce_vals<7>(v, redL, wave, lane);
            if (tid < 7) {
                astore(&part[blk * 8 + tid],
                       redL[tid * NW] + redL[tid * NW + 1] + redL[tid * NW + 2] + redL[tid * NW + 3]);
            }
            __syncthreads();
            if (tid == 0) bar_add<SH>(cnt, blk);
            tgt += NBLK;
        }

        // GEMM-A (hides barrier): R_partial = Hn + d@A_{l+1}
        gemmA<RPB, true>(Afr + (size_t)(l + 1) * 32768, Afi + (size_t)(l + 1) * 32768,
                         dbr, dbi, HreL, HimL, wave, lane, quad, m);

        bar_wait<SH>(cnt, tgt);
        float bre, bim;
        {
            float v[7];
            #pragma unroll
            for (int q = 0; q < 7; ++q) v[q] = 0.f;
            #pragma unroll
            for (int i = 0; i < PLOAD; ++i) {
                const float* pb = &part[(size_t)(tid + i * THR) * 8];
                #pragma unroll
                for (int q = 0; q < 7; ++q) v[q] += aload(pb + q);
            }
            reduce_vals<7>(v, redL, wave, lane);
            float tot[7];
            #pragma unroll
            for (int q = 0; q < 7; ++q)
                tot[q] = redL[q * NW] + redL[q * NW + 1] + redL[q * NW + 2] + redL[q * NW + 3];
            bre = th1 * tot[0] * (1.0f / 48.0f);
            bim = th1 * tot[1] * (1.0f / 48.0f);
            float sig2 = tot[2] + 2.f * bre * tot[3] + 2.f * bim * tot[4]
                       + bre * bre * tot[5] + bim * bim * tot[6];
            lam = th[(l + 1) * 3] * sqrtf(sig2 * (1.0f / 48.0f));
            th1 = th[(l + 1) * 3 + 1];
        }

        // scale pass: ẑ = b∘z into staging (reuse), z = d + b∘z in regs
        #pragma unroll
        for (int k = 0; k < ZPT; ++k) {
            int j = tid + k * THR;
            if (EXACT || j < NELEM) {
                int r = j / 48, f = j - r * 48;
                float zhr = bre * zR[k], zhi = bim * zI[k];
                dbr[r * DST + f] = f2bf(zhr);
                dbi[r * DST + f] = f2bf(zhi);
                zR[k] = dRr[k] + zhr;
                zI[k] = dIr[k] + zhi;
            }
        }
        __syncthreads();

        // GEMM-B: R = R_partial + ẑ@A_{l+1}, fused activation -> Hn_{l+1}
        cr = 0.f; ci = 0.f;
        gemmB<RPB>(Afr + (size_t)(l + 1) * 32768, Afi + (size_t)(l + 1) * 32768,
                   dbr, dbi, HreL, HimL, lam, th1, cr, ci, wave, lane, quad, m);
        __syncthreads();
    }

    // final: out = Hn_7 @ DFT
    bwd_gemm<RPB>(Dfr, Dfi, HreL, HimL, pR, pI, wave, lane, quad, m);
    __syncthreads();
    float2* out2 = (float2*)out;
    #pragma unroll
    for (int k = 0; k < ZPT; ++k) {
        int j = tid + k * THR;
        if (EXACT || j < NELEM) {
            int r = j / 48, f = j - r * 48;
            int ft = f >> 4, c = f & 15;
            out2[(row0 + r) * 48 + f] =
                make_float2(pR[(ft * 16 + r) * 17 + c], pI[(ft * 16 + r) * 17 + c]);
        }
    }
}

extern "C" void kernel_launch(void* const* d_in, const int* in_sizes, int n_in,
                              void* d_out, int out_size, void* d_ws, size_t ws_size,
                              hipStream_t stream) {
    (void)in_sizes; (void)n_in; (void)out_size; (void)ws_size;
    const float* u  = (const float*)d_in[0];
    const float* Ar = (const float*)d_in[1];
    const float* Ai = (const float*)d_in[2];
    const float* th = (const float*)d_in[3];
    const float* Dr = (const float*)d_in[4];
    const float* Di = (const float*)d_in[5];
    float* out = (float*)d_out;

    char* p = (char*)d_ws;
    auto alloc = [&](size_t bytes) -> char* {
        char* r = p;
        p += (bytes + 255) & ~(size_t)255;
        return r;
    };
    float*    part = (float*)alloc((size_t)1024 * 8 * 4);
    uint_t*   cnt  = (uint_t*)alloc(1024 * 4);      // 32 shards on 128B lines
    ushort_t* Afr = (ushort_t*)alloc((size_t)L_ * 32768 * 2);
    ushort_t* Afi = (ushort_t*)alloc((size_t)L_ * 32768 * 2);
    ushort_t* Atr = (ushort_t*)alloc((size_t)L_ * 24576 * 2);
    ushort_t* Ati = (ushort_t*)alloc((size_t)L_ * 24576 * 2);
    ushort_t* Dfr = (ushort_t*)alloc((size_t)24576 * 2);
    ushort_t* Dfi = (ushort_t*)alloc((size_t)24576 * 2);

    k_pre<<<256, 256, 0, stream>>>(Ar, Ai, Dr, Di, Afr, Afi, Atr, Ati, Dfr, Dfi, cnt);

    // LDS bytes: 6528 (pR/pI) + 128 (red) + 4608 (staging) + RPB*2080 (H)
    const int lds8  = 6528 + 128 + 4608 + 8 * 2080;    // 27904
    const int lds16 = 6528 + 128 + 4608 + 16 * 2080;   // 44544
    hipFuncSetAttribute((const void*)k_lamp<8>,
                        hipFuncAttributeMaxDynamicSharedMemorySize, lds8);
    hipFuncSetAttribute((const void*)k_lamp<16>,
                        hipFuncAttributeMaxDynamicSharedMemorySize, lds16);

    void* args[] = { (void*)&u, (void*)&Afr, (void*)&Afi, (void*)&Atr, (void*)&Ati,
                     (void*)&Dfr, (void*)&Dfi, (void*)&th,
                     (void*)&part, (void*)&cnt, (void*)&out };

    // deadlock-proof occupancy selection: RPB=8 needs 4 blocks/CU co-resident
    int nb = 0;
    hipOccupancyMaxActiveBlocksPerMultiprocessor(&nb, (const void*)k_lamp<8>, THR, (size_t)lds8);
    if (nb >= 4) {
        hipLaunchCooperativeKernel((void*)k_lamp<8>, dim3(1024), dim3(THR), args,
                                   lds8, stream);
    } else {
        hipLaunchCooperativeKernel((void*)k_lamp<16>, dim3(512), dim3(THR), args,
                                   lds16, stream);
    }
}